// Round 3
// baseline (227.342 us; speedup 1.0000x reference)
//
#include <hip/hip_runtime.h>
#include <cstdint>

#define E_EXP 8
#define BATCH 8192
#define D0 480
#define D1 512
#define D2 512
#define D3 363
#define KP 512      // padded per-expert K
#define N3PAD 384

typedef _Float16 f16x8 __attribute__((ext_vector_type(8)));
typedef float f32x16 __attribute__((ext_vector_type(16)));
typedef unsigned short u16;

__device__ __forceinline__ u16 f2h(float f) {
    _Float16 h = (_Float16)f;
    return __builtin_bit_cast(u16, h);
}

// async global->LDS, 16B per lane; LDS dest = wave-uniform base + lane*16
__device__ __forceinline__ void async16(const u16* g, u16* s) {
    __builtin_amdgcn_global_load_lds(
        reinterpret_cast<const __attribute__((address_space(1))) void*>(
            reinterpret_cast<uintptr_t>(g)),
        reinterpret_cast<__attribute__((address_space(3))) void*>(
            reinterpret_cast<uintptr_t>(s)),
        16, 0, 0);
}

// W[e][o][i] fp32 -> wf[e][o][0..511] fp16, zero-padded in o (to OUTP) and i (to 512)
__device__ __forceinline__ void pack_seg(const float* __restrict__ src,
                                         u16* __restrict__ dst,
                                         int OUT_src, int OUTP, int IN_src) {
    int total = E_EXP * OUTP * 128;
    int in4 = IN_src >> 2;
    for (int idx = blockIdx.x * blockDim.x + threadIdx.x; idx < total;
         idx += gridDim.x * blockDim.x) {
        int e = idx / (OUTP * 128);
        int r = idx - e * OUTP * 128;
        int o = r >> 7;
        int k4 = r & 127;
        ushort4 w;
        if (o < OUT_src && k4 < in4) {
            const float4 v = *reinterpret_cast<const float4*>(
                src + ((size_t)e * OUT_src + o) * IN_src + (k4 << 2));
            w.x = f2h(v.x); w.y = f2h(v.y); w.z = f2h(v.z); w.w = f2h(v.w);
        } else {
            w.x = 0; w.y = 0; w.z = 0; w.w = 0;
        }
        *reinterpret_cast<ushort4*>(dst + ((size_t)e * OUTP + o) * KP + (k4 << 2)) = w;
    }
}

__global__ void pack_all(const float* __restrict__ W1, const float* __restrict__ W2,
                         const float* __restrict__ W3, u16* __restrict__ wf1,
                         u16* __restrict__ wf2, u16* __restrict__ wf3) {
    pack_seg(W1, wf1, 512, 512, D0);
    pack_seg(W2, wf2, 512, 512, D1);
    pack_seg(W3, wf3, D3, N3PAD, D2);
}

// x (8192x480 fp32) -> xp (8192x512 fp16, zero-padded)
__global__ void pad_x(const float* __restrict__ x, u16* __restrict__ xp) {
    int total = BATCH * 128;
    for (int idx = blockIdx.x * blockDim.x + threadIdx.x; idx < total;
         idx += gridDim.x * blockDim.x) {
        int b = idx >> 7, k4 = idx & 127;
        ushort4 w;
        if (k4 < 120) {
            const float4 v = *reinterpret_cast<const float4*>(
                x + (size_t)b * D0 + (k4 << 2));
            w.x = f2h(v.x); w.y = f2h(v.y); w.z = f2h(v.z); w.w = f2h(v.w);
        } else {
            w.x = 0; w.y = 0; w.z = 0; w.w = 0;
        }
        *reinterpret_cast<ushort4*>(xp + (size_t)b * KP + (k4 << 2)) = w;
    }
}

// All-expert fused blended GEMM, double-buffered, 2 BLOCKS/CU:
//   acc[m][n] = sum_e bl[e,m] * (A @ W_e^T)[m,n]   (in-register blend on A)
// Tile 128x64, BK=32, 16 passes; 256 thr = 4 waves (2m x 2n), wave tile 64x32,
// 32x32x16 MFMA, acc split by k-half -> 4 independent chains/wave.
// LDS per buffer: As 128x32 (8KB) + Bs 8e x 64n x 32k (32KB) = 40KB; x2 = 80KB
// -> 2 resident blocks/CU (16 waves/CU, 4/SIMD). The two blocks are
// independent barrier domains: one block's __syncthreads/vmcnt drain overlaps
// the other's MFMA phase (the occupancy lever rounds 1-2 were missing).
// Grid 64*nbn (512 for N=512), XCD key on bm low bits.
__global__ __launch_bounds__(256, 2) void gemm_all(
    const u16* __restrict__ A, const u16* __restrict__ Bw,
    const float* __restrict__ blend, const float* __restrict__ bias,
    u16* __restrict__ out, int OUTP, int OUTR, int nbn, int mode) {
    __shared__ __align__(16) u16 S[40960];  // 80 KB = 2 x (As 4096 + Bs 16384 elems)
    const int tid = threadIdx.x;
    const int w = tid >> 6, lane = tid & 63;
    const int wm = w & 1, wn = w >> 1;
    const int l31 = lane & 31, q2 = lane >> 5;

    const int id = blockIdx.x;
    const int xcd = id & 7;
    const int j = id >> 3;
    const int bm = ((j & 7) << 3) + xcd;  // 0..63 (128-row tiles), pinned to XCD
    const int bn = j >> 3;                // 0..nbn-1

    f32x16 acc[2][2];  // [m-group][k-half]
#pragma unroll
    for (int mg = 0; mg < 2; ++mg)
#pragma unroll
        for (int kk = 0; kk < 2; ++kk)
#pragma unroll
            for (int i = 0; i < 16; ++i) acc[mg][kk][i] = 0.f;

    // per-lane blend scalars: row of A-fragment = lane&31 within 32-row m-group
    _Float16 blh[8][2];
#pragma unroll
    for (int e = 0; e < 8; ++e)
#pragma unroll
        for (int mg = 0; mg < 2; ++mg)
            blh[e][mg] = (_Float16)blend[e * BATCH + bm * 128 + wm * 64 +
                                         mg * 32 + l31];

    // staging geometry: 1KB chunk = 16 rows x 32k; lane = r*4 + s
    const int l4r = lane >> 2;                        // row in chunk
    const int l4s = lane & 3;                         // phys 16B slot
    const int ks8 = (l4s ^ ((l4r >> 1) & 3)) << 3;    // swizzled k elem offset
    const size_t EST = (size_t)OUTP * KP;             // expert stride in Bw
    // wave w stages: A rows [w*32, w*32+32), experts 2w and 2w+1 (64 n-rows each)
    const u16* gA0 = A + (size_t)(bm * 128 + w * 32 + l4r) * KP + ks8;
    const u16* gB0 = Bw + (size_t)(2 * w) * EST + (size_t)(bn * 64 + l4r) * KP + ks8;
    const u16* gB1 = gB0 + EST;
    const size_t R16 = (size_t)16 * KP;
    const int aBase = w * 1024;                 // As dst (elems, within buffer)
    const int bBase0 = 4096 + (2 * w) * 2048;   // Bs dst expert 2w
    const int bBase1 = bBase0 + 2048;           // Bs dst expert 2w+1

    // fragment read offsets (loop-invariant); logical k-slot = kk*2 + q2
    int aoff[2][2], boff[2];
#pragma unroll
    for (int mg = 0; mg < 2; ++mg) {
        int r = wm * 64 + mg * 32 + l31;
        int base = (r >> 4) * 512 + (r & 15) * 32;
        int swz = (r >> 1) & 3;
#pragma unroll
        for (int kk = 0; kk < 2; ++kk)
            aoff[mg][kk] = base + (((kk * 2 + q2) ^ swz) << 3);
    }
    {
        int r = wn * 32 + l31;
        int base = (r >> 4) * 512 + (r & 15) * 32;
        int swz = (r >> 1) & 3;
#pragma unroll
        for (int kk = 0; kk < 2; ++kk)
            boff[kk] = base + (((kk * 2 + q2) ^ swz) << 3);
    }

    auto stage = [&](int kt, int p) {
        const int ko = kt << 5;
        u16* buf = S + p * 20480;
        async16(gA0 + ko, buf + aBase);
        async16(gA0 + R16 + ko, buf + aBase + 512);
#pragma unroll
        for (int c = 0; c < 4; ++c) {
            async16(gB0 + c * R16 + ko, buf + bBase0 + c * 512);
            async16(gB1 + c * R16 + ko, buf + bBase1 + c * 512);
        }
    };

    stage(0, 0);
    __syncthreads();

#pragma unroll 2
    for (int kt = 0; kt < 16; ++kt) {
        const int p = kt & 1;
        if (kt < 15) stage(kt + 1, p ^ 1);
        const u16* As_ = S + p * 20480;
        const u16* Bs_ = As_ + 4096;
        f16x8 af[2][2];
#pragma unroll
        for (int mg = 0; mg < 2; ++mg)
#pragma unroll
            for (int kk = 0; kk < 2; ++kk)
                af[mg][kk] = *reinterpret_cast<const f16x8*>(&As_[aoff[mg][kk]]);
        __builtin_amdgcn_s_setprio(1);
#pragma unroll
        for (int e = 0; e < 8; ++e) {
            f16x8 bf0 = *reinterpret_cast<const f16x8*>(&Bs_[e * 2048 + boff[0]]);
            f16x8 bf1 = *reinterpret_cast<const f16x8*>(&Bs_[e * 2048 + boff[1]]);
#pragma unroll
            for (int mg = 0; mg < 2; ++mg) {
                f16x8 a0 = af[mg][0] * blh[e][mg];
                acc[mg][0] = __builtin_amdgcn_mfma_f32_32x32x16_f16(
                    a0, bf0, acc[mg][0], 0, 0, 0);
                f16x8 a1 = af[mg][1] * blh[e][mg];
                acc[mg][1] = __builtin_amdgcn_mfma_f32_32x32x16_f16(
                    a1, bf1, acc[mg][1], 0, 0, 0);
            }
        }
        __builtin_amdgcn_s_setprio(0);
        __syncthreads();
    }

    // fused epilogue: blended bias from LDS tiles (stride 9 = conflict-free),
    // optional ELU, fp16 store. C layout: col=lane&31, row=(reg&3)+8*(reg>>2)+4*q2.
    float* Blf = reinterpret_cast<float*>(S);         // [128][9]
    float* Bif = reinterpret_cast<float*>(S + 8192);  // [64][9] (byte 16384)
    for (int idx = tid; idx < 1024; idx += 256) {
        int e = idx >> 7, r = idx & 127;
        Blf[r * 9 + e] = blend[e * BATCH + bm * 128 + r];
    }
    for (int idx = tid; idx < 512; idx += 256) {
        int e = idx >> 6, c = idx & 63;
        int cg = bn * 64 + c;
        Bif[c * 9 + e] = (cg < OUTR) ? bias[e * OUTR + cg] : 0.f;
    }
    __syncthreads();

    const int col_l = wn * 32 + l31;
    const int gcol = bn * 64 + col_l;
    float bif[8];
#pragma unroll
    for (int e = 0; e < 8; ++e) bif[e] = Bif[col_l * 9 + e];
#pragma unroll
    for (int mg = 0; mg < 2; ++mg) {
#pragma unroll
        for (int reg = 0; reg < 16; ++reg) {
            int rloc = (reg & 3) + ((reg >> 2) << 3) + (q2 << 2);
            int rl = wm * 64 + mg * 32 + rloc;
            float bb = 0.f;
#pragma unroll
            for (int e = 0; e < 8; ++e) bb += Blf[rl * 9 + e] * bif[e];
            float v = acc[mg][0][reg] + acc[mg][1][reg] + bb;
            if (mode == 0) v = v > 0.f ? v : expm1f(v);
            out[(size_t)(bm * 128 + rl) * OUTP + gcol] = f2h(v);
        }
    }
}

// softmax over D3=363 of fp16 logits (bias already applied) -> fp32 out.
__global__ __launch_bounds__(128) void softmax_rows(
    const u16* __restrict__ P, float* __restrict__ out) {
    const int b = blockIdx.x;
    const int tid = threadIdx.x, lane = tid & 63, w = tid >> 6;
    float v[3];
    int n = 0;
    float mx = -3.4e38f;
    for (int i = tid; i < D3; i += 128) {
        float s = (float)*reinterpret_cast<const _Float16*>(
            P + (size_t)b * N3PAD + i);
        v[n] = s; mx = fmaxf(mx, s); ++n;
    }
#pragma unroll
    for (int off = 32; off >= 1; off >>= 1) mx = fmaxf(mx, __shfl_xor(mx, off, 64));
    __shared__ float sm[4];
    if (lane == 0) sm[w] = mx;
    __syncthreads();
    mx = fmaxf(sm[0], sm[1]);
    float s = 0.f;
    for (int jj = 0; jj < n; ++jj) { v[jj] = expf(v[jj] - mx); s += v[jj]; }
#pragma unroll
    for (int off = 32; off >= 1; off >>= 1) s += __shfl_xor(s, off, 64);
    if (lane == 0) sm[2 + w] = s;
    __syncthreads();
    float inv = 1.f / (sm[2] + sm[3]);
    n = 0;
    for (int i = tid; i < D3; i += 128) { out[(size_t)b * D3 + i] = v[n] * inv; ++n; }
}

extern "C" void kernel_launch(void* const* d_in, const int* in_sizes, int n_in,
                              void* d_out, int out_size, void* d_ws, size_t ws_size,
                              hipStream_t stream) {
    const float* x = (const float*)d_in[0];
    const float* blend = (const float*)d_in[1];
    const float* W1 = (const float*)d_in[2];
    const float* b1 = (const float*)d_in[3];
    const float* W2 = (const float*)d_in[4];
    const float* b2 = (const float*)d_in[5];
    const float* W3 = (const float*)d_in[6];
    const float* b3 = (const float*)d_in[7];
    float* outp = (float*)d_out;

    char* ws = (char*)d_ws;
    u16* wf1 = (u16*)ws; ws += (size_t)E_EXP * 512 * KP * 2;    // 4.19 MB
    u16* wf2 = (u16*)ws; ws += (size_t)E_EXP * 512 * KP * 2;    // 4.19 MB
    u16* wf3 = (u16*)ws; ws += (size_t)E_EXP * N3PAD * KP * 2;  // 3.15 MB
    u16* xp = (u16*)ws;  ws += (size_t)BATCH * KP * 2;          // 8.39 MB
    u16* h1 = (u16*)ws;  ws += (size_t)BATCH * KP * 2;          // 8.39 MB
    u16* h2 = (u16*)ws;  ws += (size_t)BATCH * KP * 2;          // 8.39 MB
    u16* P = (u16*)ws;                                          // 8192*384*2 = 6.29 MB

    pack_all<<<1024, 256, 0, stream>>>(W1, W2, W3, wf1, wf2, wf3);
    pad_x<<<2048, 256, 0, stream>>>(x, xp);

    gemm_all<<<64 * 8, 256, 0, stream>>>(xp, wf1, blend, b1, h1, 512, 512, 8, 0);
    gemm_all<<<64 * 8, 256, 0, stream>>>(h1, wf2, blend, b2, h2, 512, 512, 8, 0);
    gemm_all<<<64 * 6, 256, 0, stream>>>(h2, wf3, blend, b3, P, N3PAD, D3, 6, 1);
    softmax_rows<<<BATCH, 128, 0, stream>>>(P, outp);
}

// Round 4
// 226.274 us; speedup vs baseline: 1.0047x; 1.0047x over previous
//
#include <hip/hip_runtime.h>
#include <cstdint>

#define E_EXP 8
#define BATCH 8192
#define D0 480
#define D1 512
#define D2 512
#define D3 363
#define KP 512      // padded per-expert K
#define N3PAD 384

typedef _Float16 f16x8 __attribute__((ext_vector_type(8)));
typedef float f32x16 __attribute__((ext_vector_type(16)));
typedef unsigned short u16;

#define VMCNT(n) asm volatile("s_waitcnt vmcnt(" #n ")" ::: "memory")

__device__ __forceinline__ u16 f2h(float f) {
    _Float16 h = (_Float16)f;
    return __builtin_bit_cast(u16, h);
}

// async global->LDS, 16B per lane; LDS dest = wave-uniform base + lane*16
__device__ __forceinline__ void async16(const u16* g, u16* s) {
    __builtin_amdgcn_global_load_lds(
        reinterpret_cast<const __attribute__((address_space(1))) void*>(
            reinterpret_cast<uintptr_t>(g)),
        reinterpret_cast<__attribute__((address_space(3))) void*>(
            reinterpret_cast<uintptr_t>(s)),
        16, 0, 0);
}

// W[e][o][i] fp32 -> wf[e][o][0..511] fp16, zero-padded in o (to OUTP) and i (to 512)
__device__ __forceinline__ void pack_seg(const float* __restrict__ src,
                                         u16* __restrict__ dst,
                                         int OUT_src, int OUTP, int IN_src) {
    int total = E_EXP * OUTP * 128;
    int in4 = IN_src >> 2;
    for (int idx = blockIdx.x * blockDim.x + threadIdx.x; idx < total;
         idx += gridDim.x * blockDim.x) {
        int e = idx / (OUTP * 128);
        int r = idx - e * OUTP * 128;
        int o = r >> 7;
        int k4 = r & 127;
        ushort4 w;
        if (o < OUT_src && k4 < in4) {
            const float4 v = *reinterpret_cast<const float4*>(
                src + ((size_t)e * OUT_src + o) * IN_src + (k4 << 2));
            w.x = f2h(v.x); w.y = f2h(v.y); w.z = f2h(v.z); w.w = f2h(v.w);
        } else {
            w.x = 0; w.y = 0; w.z = 0; w.w = 0;
        }
        *reinterpret_cast<ushort4*>(dst + ((size_t)e * OUTP + o) * KP + (k4 << 2)) = w;
    }
}

__global__ void pack_all(const float* __restrict__ W1, const float* __restrict__ W2,
                         const float* __restrict__ W3, u16* __restrict__ wf1,
                         u16* __restrict__ wf2, u16* __restrict__ wf3) {
    pack_seg(W1, wf1, 512, 512, D0);
    pack_seg(W2, wf2, 512, 512, D1);
    pack_seg(W3, wf3, D3, N3PAD, D2);
}

// x (8192x480 fp32) -> xp (8192x512 fp16, zero-padded)
__global__ void pad_x(const float* __restrict__ x, u16* __restrict__ xp) {
    int total = BATCH * 128;
    for (int idx = blockIdx.x * blockDim.x + threadIdx.x; idx < total;
         idx += gridDim.x * blockDim.x) {
        int b = idx >> 7, k4 = idx & 127;
        ushort4 w;
        if (k4 < 120) {
            const float4 v = *reinterpret_cast<const float4*>(
                x + (size_t)b * D0 + (k4 << 2));
            w.x = f2h(v.x); w.y = f2h(v.y); w.z = f2h(v.z); w.w = f2h(v.w);
        } else {
            w.x = 0; w.y = 0; w.z = 0; w.w = 0;
        }
        *reinterpret_cast<ushort4*>(xp + (size_t)b * KP + (k4 << 2)) = w;
    }
}

// All-expert fused blended GEMM -- 4-PHASE interleaved K-loop (T3+T4+T5):
//   acc[m][n] = sum_e bl[e,m] * (A @ W_e^T)[m,n]   (in-register blend on A)
// Tile 256x64; 8 waves = 4m x 2n, wave tile 64x32, 32x32x16 MFMA, acc split
// by k-half -> 4 independent chains/wave. TRIPLE-buffered (3 x 48KB = 144KB).
// Each kt = 4 phases (one expert-pair each):
//   { ds_read this phase's frags (4-8 b128); issue 3 async16 (ph 0/1 only);
//     s_barrier; setprio(1); 8 MFMA; setprio(0); s_barrier }
// Counted vmcnt(6) ONCE per kt after phase-3 MFMA: drains stage(kt+1), leaves
// stage(kt+2)'s 6 loads in flight across the barrier (never 0 in steady
// state). Small barrier windows bound wave skew so one wave's lgkm wait
// overlaps its SIMD-partner's MFMA burst (the m201/8-phase mechanism) --
// this per-phase interleave is what rounds 1-2 lacked.
// Buffer hazards: kt reads buf kt%3; stage writes buf (kt+2)%3; last reads of
// that buffer were in kt-1 and are sequenced before the end-of-(kt-1) barrier,
// which precedes the stage issue in kt phase 0. Grid 32*nbn, XCD key on bm.
__global__ __launch_bounds__(512, 2) void gemm_all(
    const u16* __restrict__ A, const u16* __restrict__ Bw,
    const float* __restrict__ blend, const float* __restrict__ bias,
    u16* __restrict__ out, int OUTP, int OUTR, int nbn, int mode) {
    __shared__ __align__(16) u16 S[73728];  // 144 KB = 3 x (As 8192 + Bs 16384)
    const int tid = threadIdx.x;
    const int w = tid >> 6, lane = tid & 63;
    const int wm2 = w & 3, wn2 = w >> 2;
    const int l31 = lane & 31, q2 = lane >> 5;

    const int id = blockIdx.x;
    const int xcd = id & 7;
    const int j = id >> 3;
    const int bm = ((j & 3) << 3) + xcd;  // 0..31 (256-row tiles), pinned to XCD
    const int bn = j >> 2;                // 0..nbn-1

    f32x16 acc[2][2];  // [m-group][k-half]
#pragma unroll
    for (int mg = 0; mg < 2; ++mg)
#pragma unroll
        for (int kk = 0; kk < 2; ++kk)
#pragma unroll
            for (int i = 0; i < 16; ++i) acc[mg][kk][i] = 0.f;

    // per-lane blend scalars: row of A-fragment = lane&31 within 32-row m-group
    _Float16 blh[8][2];
#pragma unroll
    for (int e = 0; e < 8; ++e)
#pragma unroll
        for (int mg = 0; mg < 2; ++mg)
            blh[e][mg] = (_Float16)blend[e * BATCH + bm * 256 + wm2 * 64 +
                                         mg * 32 + l31];

    // staging geometry: 1KB chunk = 16 rows x 32k; lane = r*4 + s
    const int l4r = lane >> 2;                        // row in chunk
    const int l4s = lane & 3;                         // phys 16B slot
    const int ks8 = (l4s ^ ((l4r >> 1) & 3)) << 3;    // swizzled k elem offset
    const size_t EST = (size_t)OUTP * KP;             // expert stride in Bw
    const u16* gA0 = A + (size_t)(bm * 256 + w * 32 + l4r) * KP + ks8;
    const u16* gB0 = Bw + (size_t)w * EST + (size_t)(bn * 64 + l4r) * KP + ks8;
    const size_t R16 = (size_t)16 * KP;
    const int aBase = w * 1024;                // As dst (elems, within buffer)
    const int bBase = 8192 + w * 2048;         // Bs dst (wave w stages expert w)

    // fragment read offsets (loop-invariant); logical k-slot = kk*2 + q2
    int aoff[2][2], boff[2];
#pragma unroll
    for (int mg = 0; mg < 2; ++mg) {
        int r = wm2 * 64 + mg * 32 + l31;
        int base = (r >> 4) * 512 + (r & 15) * 32;
        int swz = (r >> 1) & 3;
#pragma unroll
        for (int kk = 0; kk < 2; ++kk)
            aoff[mg][kk] = base + (((kk * 2 + q2) ^ swz) << 3);
    }
    {
        int r = wn2 * 32 + l31;
        int base = (r >> 4) * 512 + (r & 15) * 32;
        int swz = (r >> 1) & 3;
#pragma unroll
        for (int kk = 0; kk < 2; ++kk)
            boff[kk] = base + (((kk * 2 + q2) ^ swz) << 3);
    }

    auto stage = [&](int kt, int b) {
        const int ko = kt << 5;
        u16* buf = S + b * 24576;
        async16(gA0 + ko, buf + aBase);
        async16(gA0 + R16 + ko, buf + aBase + 512);
        async16(gB0 + ko, buf + bBase);
        async16(gB0 + R16 + ko, buf + bBase + 512);
        async16(gB0 + 2 * R16 + ko, buf + bBase + 1024);
        async16(gB0 + 3 * R16 + ko, buf + bBase + 1536);
    };

    // prologue: two tiles in flight, drain only the first
    stage(0, 0);
    stage(1, 1);
    VMCNT(6);
    __builtin_amdgcn_s_barrier();
    __builtin_amdgcn_sched_barrier(0);

#pragma unroll
    for (int kt = 0; kt < 16; ++kt) {
        const int p = kt % 3;
        const u16* As_ = S + p * 24576;
        const u16* Bs_ = As_ + 8192;
        u16* nbuf = S + ((kt + 2) % 3) * 24576;
        const int ko2 = (kt + 2) << 5;
        f16x8 af[2][2];
#pragma unroll
        for (int ph = 0; ph < 4; ++ph) {
            // ---- per-phase ds_reads (this phase's operands) ----
            if (ph == 0) {
#pragma unroll
                for (int mg = 0; mg < 2; ++mg)
#pragma unroll
                    for (int kk = 0; kk < 2; ++kk)
                        af[mg][kk] =
                            *reinterpret_cast<const f16x8*>(&As_[aoff[mg][kk]]);
            }
            f16x8 bf[2][2];  // [e-in-pair][kk]
#pragma unroll
            for (int ee = 0; ee < 2; ++ee)
#pragma unroll
                for (int kk = 0; kk < 2; ++kk)
                    bf[ee][kk] = *reinterpret_cast<const f16x8*>(
                        &Bs_[(2 * ph + ee) * 2048 + boff[kk]]);
            // ---- staging split across phases 0 and 1 ----
            if (kt < 14) {
                if (ph == 0) {
                    async16(gA0 + ko2, nbuf + aBase);
                    async16(gA0 + R16 + ko2, nbuf + aBase + 512);
                    async16(gB0 + ko2, nbuf + bBase);
                } else if (ph == 1) {
                    async16(gB0 + R16 + ko2, nbuf + bBase + 512);
                    async16(gB0 + 2 * R16 + ko2, nbuf + bBase + 1024);
                    async16(gB0 + 3 * R16 + ko2, nbuf + bBase + 1536);
                }
            }
            __builtin_amdgcn_sched_barrier(0);
            __builtin_amdgcn_s_barrier();
            __builtin_amdgcn_sched_barrier(0);
            // ---- MFMA burst for this expert pair ----
            __builtin_amdgcn_s_setprio(1);
#pragma unroll
            for (int ee = 0; ee < 2; ++ee) {
                const int e = 2 * ph + ee;
#pragma unroll
                for (int mg = 0; mg < 2; ++mg) {
                    f16x8 a0 = af[mg][0] * blh[e][mg];
                    acc[mg][0] = __builtin_amdgcn_mfma_f32_32x32x16_f16(
                        a0, bf[ee][0], acc[mg][0], 0, 0, 0);
                    f16x8 a1 = af[mg][1] * blh[e][mg];
                    acc[mg][1] = __builtin_amdgcn_mfma_f32_32x32x16_f16(
                        a1, bf[ee][1], acc[mg][1], 0, 0, 0);
                }
            }
            __builtin_amdgcn_s_setprio(0);
            __builtin_amdgcn_sched_barrier(0);
            // counted wait once per kt: drains stage(kt+1); stage(kt+2)'s 6
            // loads stay in flight across the barrier.
            if (ph == 3) {
                if (kt < 14) { VMCNT(6); }
                else if (kt == 14) { VMCNT(0); }
            }
            __builtin_amdgcn_s_barrier();
            __builtin_amdgcn_sched_barrier(0);
        }
    }

    // fused epilogue: blended bias from LDS tiles (stride 9 = conflict-free),
    // optional ELU, fp16 store. C layout: col=lane&31, row=(reg&3)+8*(reg>>2)+4*q2.
    float* Blf = reinterpret_cast<float*>(S);         // [256][9]
    float* Bif = reinterpret_cast<float*>(S + 8192);  // [64][9] (byte 16384)
    for (int idx = tid; idx < 2048; idx += 512) {
        int e = idx >> 8, r = idx & 255;
        Blf[r * 9 + e] = blend[e * BATCH + bm * 256 + r];
    }
    {
        int e = tid >> 6, c = tid & 63;
        int cg = bn * 64 + c;
        Bif[c * 9 + e] = (cg < OUTR) ? bias[e * OUTR + cg] : 0.f;
    }
    __syncthreads();

    const int col_l = wn2 * 32 + l31;
    const int gcol = bn * 64 + col_l;
    float bif[8];
#pragma unroll
    for (int e = 0; e < 8; ++e) bif[e] = Bif[col_l * 9 + e];
#pragma unroll
    for (int mg = 0; mg < 2; ++mg) {
#pragma unroll
        for (int reg = 0; reg < 16; ++reg) {
            int rloc = (reg & 3) + ((reg >> 2) << 3) + (q2 << 2);
            int rl = wm2 * 64 + mg * 32 + rloc;
            float bb = 0.f;
#pragma unroll
            for (int e = 0; e < 8; ++e) bb += Blf[rl * 9 + e] * bif[e];
            float v = acc[mg][0][reg] + acc[mg][1][reg] + bb;
            if (mode == 0) v = v > 0.f ? v : expm1f(v);
            out[(size_t)(bm * 256 + rl) * OUTP + gcol] = f2h(v);
        }
    }
}

// softmax over D3=363 of fp16 logits (bias already applied) -> fp32 out.
__global__ __launch_bounds__(128) void softmax_rows(
    const u16* __restrict__ P, float* __restrict__ out) {
    const int b = blockIdx.x;
    const int tid = threadIdx.x, lane = tid & 63, w = tid >> 6;
    float v[3];
    int n = 0;
    float mx = -3.4e38f;
    for (int i = tid; i < D3; i += 128) {
        float s = (float)*reinterpret_cast<const _Float16*>(
            P + (size_t)b * N3PAD + i);
        v[n] = s; mx = fmaxf(mx, s); ++n;
    }
#pragma unroll
    for (int off = 32; off >= 1; off >>= 1) mx = fmaxf(mx, __shfl_xor(mx, off, 64));
    __shared__ float sm[4];
    if (lane == 0) sm[w] = mx;
    __syncthreads();
    mx = fmaxf(sm[0], sm[1]);
    float s = 0.f;
    for (int jj = 0; jj < n; ++jj) { v[jj] = expf(v[jj] - mx); s += v[jj]; }
#pragma unroll
    for (int off = 32; off >= 1; off >>= 1) s += __shfl_xor(s, off, 64);
    if (lane == 0) sm[2 + w] = s;
    __syncthreads();
    float inv = 1.f / (sm[2] + sm[3]);
    n = 0;
    for (int i = tid; i < D3; i += 128) { out[(size_t)b * D3 + i] = v[n] * inv; ++n; }
}

extern "C" void kernel_launch(void* const* d_in, const int* in_sizes, int n_in,
                              void* d_out, int out_size, void* d_ws, size_t ws_size,
                              hipStream_t stream) {
    const float* x = (const float*)d_in[0];
    const float* blend = (const float*)d_in[1];
    const float* W1 = (const float*)d_in[2];
    const float* b1 = (const float*)d_in[3];
    const float* W2 = (const float*)d_in[4];
    const float* b2 = (const float*)d_in[5];
    const float* W3 = (const float*)d_in[6];
    const float* b3 = (const float*)d_in[7];
    float* outp = (float*)d_out;

    char* ws = (char*)d_ws;
    u16* wf1 = (u16*)ws; ws += (size_t)E_EXP * 512 * KP * 2;    // 4.19 MB
    u16* wf2 = (u16*)ws; ws += (size_t)E_EXP * 512 * KP * 2;    // 4.19 MB
    u16* wf3 = (u16*)ws; ws += (size_t)E_EXP * N3PAD * KP * 2;  // 3.15 MB
    u16* xp = (u16*)ws;  ws += (size_t)BATCH * KP * 2;          // 8.39 MB
    u16* h1 = (u16*)ws;  ws += (size_t)BATCH * KP * 2;          // 8.39 MB
    u16* h2 = (u16*)ws;  ws += (size_t)BATCH * KP * 2;          // 8.39 MB
    u16* P = (u16*)ws;                                          // 8192*384*2 = 6.29 MB

    pack_all<<<1024, 256, 0, stream>>>(W1, W2, W3, wf1, wf2, wf3);
    pad_x<<<2048, 256, 0, stream>>>(x, xp);

    gemm_all<<<32 * 8, 512, 0, stream>>>(xp, wf1, blend, b1, h1, 512, 512, 8, 0);
    gemm_all<<<32 * 8, 512, 0, stream>>>(h1, wf2, blend, b2, h2, 512, 512, 8, 0);
    gemm_all<<<32 * 6, 512, 0, stream>>>(h2, wf3, blend, b3, P, N3PAD, D3, 6, 1);
    softmax_rows<<<BATCH, 128, 0, stream>>>(P, outp);
}

// Round 5
// 215.746 us; speedup vs baseline: 1.0538x; 1.0488x over previous
//
#include <hip/hip_runtime.h>
#include <cstdint>

#define E_EXP 8
#define BATCH 8192
#define D0 480
#define D1 512
#define D2 512
#define D3 363
#define KP 512      // padded per-expert K
#define N3PAD 384

typedef _Float16 f16x8 __attribute__((ext_vector_type(8)));
typedef float f32x4 __attribute__((ext_vector_type(4)));
typedef unsigned short u16;
typedef u16 u16x8 __attribute__((ext_vector_type(8)));

__device__ __forceinline__ u16 f2h(float f) {
    _Float16 h = (_Float16)f;
    return __builtin_bit_cast(u16, h);
}

// async global->LDS, 16B per lane; LDS dest = wave-uniform base + lane*16
__device__ __forceinline__ void async16(const u16* g, u16* s) {
    __builtin_amdgcn_global_load_lds(
        reinterpret_cast<const __attribute__((address_space(1))) void*>(
            reinterpret_cast<uintptr_t>(g)),
        reinterpret_cast<__attribute__((address_space(3))) void*>(
            reinterpret_cast<uintptr_t>(s)),
        16, 0, 0);
}

// W[e][o][i] fp32 -> wf[e][o][0..511] fp16, zero-padded in o (to OUTP) and i (to 512)
__device__ __forceinline__ void pack_seg(const float* __restrict__ src,
                                         u16* __restrict__ dst,
                                         int OUT_src, int OUTP, int IN_src) {
    int total = E_EXP * OUTP * 128;
    int in4 = IN_src >> 2;
    for (int idx = blockIdx.x * blockDim.x + threadIdx.x; idx < total;
         idx += gridDim.x * blockDim.x) {
        int e = idx / (OUTP * 128);
        int r = idx - e * OUTP * 128;
        int o = r >> 7;
        int k4 = r & 127;
        ushort4 w;
        if (o < OUT_src && k4 < in4) {
            const float4 v = *reinterpret_cast<const float4*>(
                src + ((size_t)e * OUT_src + o) * IN_src + (k4 << 2));
            w.x = f2h(v.x); w.y = f2h(v.y); w.z = f2h(v.z); w.w = f2h(v.w);
        } else {
            w.x = 0; w.y = 0; w.z = 0; w.w = 0;
        }
        *reinterpret_cast<ushort4*>(dst + ((size_t)e * OUTP + o) * KP + (k4 << 2)) = w;
    }
}

// One prep kernel: pack W1/W2/W3 fp32->fp16(padded) AND pad x (fused pad_x
// rider -- saves one dispatch + launch gap; all segments are independent
// grid-stride streams).
__global__ void pack_all(const float* __restrict__ x,
                         const float* __restrict__ W1, const float* __restrict__ W2,
                         const float* __restrict__ W3, u16* __restrict__ xp,
                         u16* __restrict__ wf1, u16* __restrict__ wf2,
                         u16* __restrict__ wf3) {
    pack_seg(W1, wf1, 512, 512, D0);
    pack_seg(W2, wf2, 512, 512, D1);
    pack_seg(W3, wf3, D3, N3PAD, D2);
    // x (8192x480 fp32) -> xp (8192x512 fp16, zero-padded)
    int total = BATCH * 128;
    for (int idx = blockIdx.x * blockDim.x + threadIdx.x; idx < total;
         idx += gridDim.x * blockDim.x) {
        int b = idx >> 7, k4 = idx & 127;
        ushort4 w;
        if (k4 < 120) {
            const float4 v = *reinterpret_cast<const float4*>(
                x + (size_t)b * D0 + (k4 << 2));
            w.x = f2h(v.x); w.y = f2h(v.y); w.z = f2h(v.z); w.w = f2h(v.w);
        } else {
            w.x = 0; w.y = 0; w.z = 0; w.w = 0;
        }
        *reinterpret_cast<ushort4*>(xp + (size_t)b * KP + (k4 << 2)) = w;
    }
}

// All-expert fused blended GEMM, DOUBLE-BUFFERED (BK=32, 16 passes):
//   acc[m][n] = sum_e bl[e,m] * (A @ W_e^T)[m,n]   (in-register blend on A)
//   out = mode0: elu(acc+blended_bias) fp16 (next h); mode1: acc+bias fp16 logits
// Tile 256x64; per 48KB buffer: As 256x32 + Bs 8e x 64n x 32k; 2 buffers = 96KB.
// Prefetch pass kt+1 issued BEFORE compute of pass kt -> drain at barrier is
// covered by ~1.5k cycles of MFMA. 512 thr = 8 waves (4m x 2n). Grid 32*nbn,
// 1 block/CU, XCD key on bm.
// [session note: this body is the harness-verified best (43.0 us/gemm,
//  215.2 total). Rounds 1-4 falsified: 32x32x16 shape (-6%), counted-vmcnt
//  alone (neutral), 128-row tile "occupancy" (-5%), 4-phase interleave
//  (-130%, barrier density + I$). Do not re-touch the K-loop without new
//  counter evidence.]
__global__ __launch_bounds__(512, 2) void gemm_all(
    const u16* __restrict__ A, const u16* __restrict__ Bw,
    const float* __restrict__ blend, const float* __restrict__ bias,
    u16* __restrict__ out, int OUTP, int OUTR, int nbn, int mode) {
    __shared__ __align__(16) u16 S[49152];  // 96 KB = 2 x (As 8192 + Bs 16384)
    const int tid = threadIdx.x;
    const int w = tid >> 6, lane = tid & 63;
    const int wm2 = w & 3, wn2 = w >> 2;
    const int q = lane >> 4, l15 = lane & 15;

    const int id = blockIdx.x;
    const int xcd = id & 7;
    const int j = id >> 3;
    const int bm = ((j & 3) << 3) + xcd;  // 0..31 (256-row tiles), pinned to XCD
    const int bn = j >> 2;                // 0..nbn-1

    f32x4 acc[4][2];
#pragma unroll
    for (int mi = 0; mi < 4; ++mi)
#pragma unroll
        for (int ni = 0; ni < 2; ++ni) acc[mi][ni] = (f32x4){0.f, 0.f, 0.f, 0.f};

    // per-lane blend scalars: blh[e][mi] = blend[e, bm*256 + wm2*64 + mi*16 + l15]
    _Float16 blh[8][4];
#pragma unroll
    for (int e = 0; e < 8; ++e)
#pragma unroll
        for (int mi = 0; mi < 4; ++mi)
            blh[e][mi] = (_Float16)blend[e * BATCH + bm * 256 + wm2 * 64 +
                                         mi * 16 + l15];

    // staging geometry: 1KB chunk = 16 rows x 32k; lane = r*4 + s
    const int l4r = lane >> 2;                 // row in chunk
    const int l4s = lane & 3;                  // phys slot
    const int ks8 = (l4s ^ (l4r & 3)) << 3;    // swizzled k elem offset
    const size_t EST = (size_t)OUTP * KP;      // expert stride in Bw
    const u16* gA0 = A + (size_t)(bm * 256 + w * 32 + l4r) * KP + ks8;
    const u16* gB0 = Bw + (size_t)w * EST + (size_t)(bn * 64 + l4r) * KP + ks8;
    const size_t R16 = (size_t)16 * KP;
    const int aBase = w * 1024;                // As dst (elems, within buffer)
    const int bBase = 8192 + w * 2048;         // Bs dst

    // fragment read offsets (loop-invariant)
    const int ra = (q ^ (l15 & 3)) << 3;       // swizzled k-slot for reads
    const int arow[4] = {(wm2 * 64 + 0 * 16 + l15) * 32 + ra,
                         (wm2 * 64 + 1 * 16 + l15) * 32 + ra,
                         (wm2 * 64 + 2 * 16 + l15) * 32 + ra,
                         (wm2 * 64 + 3 * 16 + l15) * 32 + ra};
    const int brow0 = (wn2 * 32 + l15) * 32 + ra;
    const int brow1 = (wn2 * 32 + 16 + l15) * 32 + ra;

    auto stage = [&](int kt, int p) {
        const int ko = kt << 5;
        u16* buf = S + p * 24576;
        async16(gA0 + ko, buf + aBase);
        async16(gA0 + R16 + ko, buf + aBase + 512);
        async16(gB0 + ko, buf + bBase);
        async16(gB0 + R16 + ko, buf + bBase + 512);
        async16(gB0 + 2 * R16 + ko, buf + bBase + 1024);
        async16(gB0 + 3 * R16 + ko, buf + bBase + 1536);
    };

    stage(0, 0);
    __syncthreads();

#pragma unroll 2
    for (int kt = 0; kt < 16; ++kt) {
        const int p = kt & 1;
        if (kt < 15) stage(kt + 1, p ^ 1);
        const u16* As_ = S + p * 24576;
        const u16* Bs_ = As_ + 8192;
        f16x8 af[4];
#pragma unroll
        for (int mi = 0; mi < 4; ++mi)
            af[mi] = *reinterpret_cast<const f16x8*>(&As_[arow[mi]]);
#pragma unroll
        for (int e = 0; e < 8; ++e) {
            f16x8 bf0 = *reinterpret_cast<const f16x8*>(&Bs_[e * 2048 + brow0]);
            f16x8 bf1 = *reinterpret_cast<const f16x8*>(&Bs_[e * 2048 + brow1]);
#pragma unroll
            for (int mi = 0; mi < 4; ++mi) {
                f16x8 as = af[mi] * blh[e][mi];
                acc[mi][0] = __builtin_amdgcn_mfma_f32_16x16x32_f16(
                    as, bf0, acc[mi][0], 0, 0, 0);
                acc[mi][1] = __builtin_amdgcn_mfma_f32_16x16x32_f16(
                    as, bf1, acc[mi][1], 0, 0, 0);
            }
        }
        __syncthreads();
    }

    // fused epilogue: blended bias from LDS tiles, optional ELU, fp16 store
    float* Blf = reinterpret_cast<float*>(S);           // [256][8]
    float* Bif = reinterpret_cast<float*>(S + 16384);   // [64][8] (32 KB in)
    for (int idx = tid; idx < 2048; idx += 512) {
        int e = idx >> 8, r = idx & 255;
        Blf[r * 8 + e] = blend[e * BATCH + bm * 256 + r];
    }
    {
        int e = tid >> 6, c = tid & 63;
        int cg = bn * 64 + c;
        Bif[c * 8 + e] = (cg < OUTR) ? bias[e * OUTR + cg] : 0.f;
    }
    __syncthreads();
#pragma unroll
    for (int mi = 0; mi < 4; ++mi) {
#pragma unroll
        for (int ni = 0; ni < 2; ++ni) {
            int col_l = wn2 * 32 + ni * 16 + l15;
            int gcol = bn * 64 + col_l;
#pragma unroll
            for (int r = 0; r < 4; ++r) {
                int rl = wm2 * 64 + mi * 16 + q * 4 + r;
                float bb = 0.f;
#pragma unroll
                for (int e = 0; e < 8; ++e)
                    bb += Blf[rl * 8 + e] * Bif[col_l * 8 + e];
                float v = acc[mi][ni][r] + bb;
                if (mode == 0) v = v > 0.f ? v : expm1f(v);
                out[(size_t)(bm * 256 + rl) * OUTP + gcol] = f2h(v);
            }
        }
    }
}

// softmax over D3=363 of fp16 logits (bias already applied) -> fp32 out.
__global__ __launch_bounds__(128) void softmax_rows(
    const u16* __restrict__ P, float* __restrict__ out) {
    const int b = blockIdx.x;
    const int tid = threadIdx.x, lane = tid & 63, w = tid >> 6;
    float v[3];
    int n = 0;
    float mx = -3.4e38f;
    for (int i = tid; i < D3; i += 128) {
        float s = (float)*reinterpret_cast<const _Float16*>(
            P + (size_t)b * N3PAD + i);
        v[n] = s; mx = fmaxf(mx, s); ++n;
    }
#pragma unroll
    for (int off = 32; off >= 1; off >>= 1) mx = fmaxf(mx, __shfl_xor(mx, off, 64));
    __shared__ float sm[4];
    if (lane == 0) sm[w] = mx;
    __syncthreads();
    mx = fmaxf(sm[0], sm[1]);
    float s = 0.f;
    for (int jj = 0; jj < n; ++jj) { v[jj] = expf(v[jj] - mx); s += v[jj]; }
#pragma unroll
    for (int off = 32; off >= 1; off >>= 1) s += __shfl_xor(s, off, 64);
    if (lane == 0) sm[2 + w] = s;
    __syncthreads();
    float inv = 1.f / (sm[2] + sm[3]);
    n = 0;
    for (int i = tid; i < D3; i += 128) { out[(size_t)b * D3 + i] = v[n] * inv; ++n; }
}

extern "C" void kernel_launch(void* const* d_in, const int* in_sizes, int n_in,
                              void* d_out, int out_size, void* d_ws, size_t ws_size,
                              hipStream_t stream) {
    const float* x = (const float*)d_in[0];
    const float* blend = (const float*)d_in[1];
    const float* W1 = (const float*)d_in[2];
    const float* b1 = (const float*)d_in[3];
    const float* W2 = (const float*)d_in[4];
    const float* b2 = (const float*)d_in[5];
    const float* W3 = (const float*)d_in[6];
    const float* b3 = (const float*)d_in[7];
    float* outp = (float*)d_out;

    char* ws = (char*)d_ws;
    u16* wf1 = (u16*)ws; ws += (size_t)E_EXP * 512 * KP * 2;    // 4.19 MB
    u16* wf2 = (u16*)ws; ws += (size_t)E_EXP * 512 * KP * 2;    // 4.19 MB
    u16* wf3 = (u16*)ws; ws += (size_t)E_EXP * N3PAD * KP * 2;  // 3.15 MB
    u16* xp = (u16*)ws;  ws += (size_t)BATCH * KP * 2;          // 8.39 MB
    u16* h1 = (u16*)ws;  ws += (size_t)BATCH * KP * 2;          // 8.39 MB
    u16* h2 = (u16*)ws;  ws += (size_t)BATCH * KP * 2;          // 8.39 MB
    u16* P = (u16*)ws;                                          // 8192*384*2 = 6.29 MB

    pack_all<<<2048, 256, 0, stream>>>(x, W1, W2, W3, xp, wf1, wf2, wf3);

    gemm_all<<<32 * 8, 512, 0, stream>>>(xp, wf1, blend, b1, h1, 512, 512, 8, 0);
    gemm_all<<<32 * 8, 512, 0, stream>>>(h1, wf2, blend, b2, h2, 512, 512, 8, 0);
    gemm_all<<<32 * 6, 512, 0, stream>>>(h2, wf3, blend, b3, P, N3PAD, D3, 6, 1);
    softmax_rows<<<BATCH, 128, 0, stream>>>(P, outp);
}